// Round 8
// baseline (2998.988 us; speedup 1.0000x reference)
//
#include <hip/hip_runtime.h>
#include <hip/hip_bf16.h>
#include <stdint.h>

typedef unsigned short u16;
typedef __fp16 h2 __attribute__((ext_vector_type(2)));  // matches cvt_pkrtz/fdot2 builtin types

#define NB  32
#define NT  4096
#define NDZ 128
#define NG  384   // 3*DZ
#define NIN 192   // IN_DIM

#if defined(__has_builtin)
#if __has_builtin(__builtin_amdgcn_fdot2)
#define HAS_FDOT2 1
#endif
#endif

// ---------- helpers ----------
__device__ __forceinline__ float fast_rcp(float x) { return __builtin_amdgcn_rcpf(x); }
__device__ __forceinline__ float sigmoid_f(float x) { return fast_rcp(1.f + __expf(-x)); }
__device__ __forceinline__ float tanh_f(float x) {
  return 1.f - 2.f * fast_rcp(1.f + __expf(2.f * x));
}
__device__ __forceinline__ u16 f2bf(float f) {
  unsigned u = __float_as_uint(f);
  return (u16)((u + 0x7fffu + ((u >> 16) & 1u)) >> 16);
}
__device__ __forceinline__ float bf2f(u16 u) { return __uint_as_float((unsigned)u << 16); }
__device__ __forceinline__ u16 f2h16(float f) {
  __fp16 h = (__fp16)f;                 // v_cvt_f16_f32
  return __builtin_bit_cast(u16, h);
}
__device__ __forceinline__ float fdot2f(h2 a, h2 b, float c) {
#ifdef HAS_FDOT2
  return __builtin_amdgcn_fdot2(a, b, c, false);
#else
  return __builtin_fmaf((float)a.x, (float)b.x,
         __builtin_fmaf((float)a.y, (float)b.y, c));
#endif
}

// LDS-only barrier (ds ops drained via lgkmcnt; vmcnt stays in flight so the
// t+2 gi prefetch and traj stores cross barriers without draining).
__device__ __forceinline__ void bar_lds() {
  asm volatile("s_waitcnt lgkmcnt(0)\n\ts_barrier" ::: "memory");
}

// gi workspace: bf16 validated (absmax 3.9e-3 << 5.9e-2); f32 if ws allows
__device__ __forceinline__ float giload(const float* p) { return *p; }
__device__ __forceinline__ float giload(const u16* p)   { return bf2f(*p); }
__device__ __forceinline__ void store8(float* p, const float* v) {
  float4 a = {v[0], v[1], v[2], v[3]}, b = {v[4], v[5], v[6], v[7]};
  *(float4*)p = a; *(float4*)(p + 4) = b;
}
__device__ __forceinline__ void store8(u16* p, const float* v) {
  uint4 o;
  o.x = (unsigned)f2bf(v[0]) | ((unsigned)f2bf(v[1]) << 16);
  o.y = (unsigned)f2bf(v[2]) | ((unsigned)f2bf(v[3]) << 16);
  o.z = (unsigned)f2bf(v[4]) | ((unsigned)f2bf(v[5]) << 16);
  o.w = (unsigned)f2bf(v[6]) | ((unsigned)f2bf(v[7]) << 16);
  *(uint4*)p = o;
}

// ---------- Phase 1: gi = x @ W_ih^T + b_ih (unchanged) ----------
#define GM 128
#define GN 128
#define LDSS 132

template <typename GT>
__global__ __launch_bounds__(256) void gemm_gi(
    const float* __restrict__ Y, const float* __restrict__ M,
    const float* __restrict__ H, const float* __restrict__ Wih,
    const float* __restrict__ bih, GT* __restrict__ gi)
{
  __shared__ float As[32 * LDSS];
  __shared__ float Bs[32 * LDSS];
  const int tid = threadIdx.x;
  const size_t m0 = (size_t)blockIdx.x * GM;
  const int n0 = blockIdx.y * GN;
  const int tm = tid & 15;
  const int tn = tid >> 4;

  float acc[8][8];
#pragma unroll
  for (int i = 0; i < 8; ++i)
#pragma unroll
    for (int j = 0; j < 8; ++j) acc[i][j] = 0.f;

#pragma unroll
  for (int kc = 0; kc < 6; ++kc) {
    const float* src; int stride; int off;
    if (kc == 0)      { src = Y; stride = 32;  off = 0; }
    else if (kc == 1) { src = M; stride = 32;  off = 0; }
    else              { src = H; stride = 128; off = (kc - 2) * 32; }
#pragma unroll
    for (int it = 0; it < 4; ++it) {
      int x = tid + it * 256;
      int row = x >> 3, q = x & 7;
      float4 v = *(const float4*)(src + (m0 + (size_t)row) * stride + off + q * 4);
      As[(q * 4 + 0) * LDSS + row] = v.x;
      As[(q * 4 + 1) * LDSS + row] = v.y;
      As[(q * 4 + 2) * LDSS + row] = v.z;
      As[(q * 4 + 3) * LDSS + row] = v.w;
    }
#pragma unroll
    for (int it = 0; it < 4; ++it) {
      int x = tid + it * 256;
      int g = x >> 3, q = x & 7;
      float4 v = *(const float4*)(Wih + (size_t)(n0 + g) * NIN + kc * 32 + q * 4);
      Bs[(q * 4 + 0) * LDSS + g] = v.x;
      Bs[(q * 4 + 1) * LDSS + g] = v.y;
      Bs[(q * 4 + 2) * LDSS + g] = v.z;
      Bs[(q * 4 + 3) * LDSS + g] = v.w;
    }
    __syncthreads();
#pragma unroll
    for (int kk = 0; kk < 32; ++kk) {
      float4 a0 = *(const float4*)&As[kk * LDSS + tm * 8];
      float4 a1 = *(const float4*)&As[kk * LDSS + tm * 8 + 4];
      float4 b0 = *(const float4*)&Bs[kk * LDSS + tn * 8];
      float4 b1 = *(const float4*)&Bs[kk * LDSS + tn * 8 + 4];
      float av[8] = {a0.x, a0.y, a0.z, a0.w, a1.x, a1.y, a1.z, a1.w};
      float bv[8] = {b0.x, b0.y, b0.z, b0.w, b1.x, b1.y, b1.z, b1.w};
#pragma unroll
      for (int i = 0; i < 8; ++i)
#pragma unroll
        for (int j = 0; j < 8; ++j)
          acc[i][j] = __builtin_fmaf(av[i], bv[j], acc[i][j]);
    }
    __syncthreads();
  }
  float bv[8];
#pragma unroll
  for (int j = 0; j < 8; ++j) bv[j] = bih[n0 + tn * 8 + j];
#pragma unroll
  for (int i = 0; i < 8; ++i) {
    size_t row = m0 + (size_t)(tm * 8 + i);
    GT* o = gi + row * NG + n0 + tn * 8;
    float v[8];
#pragma unroll
    for (int j = 0; j < 8; ++j) v[j] = acc[i][j] + bv[j];
    store8(o, v);
  }
}

// ---------- Phase 2: scan, 2 waves/block, z-exchange, lane-local gates ----------
// R6 post-mortem: active step ~2900 cyc vs ~230 cyc/wave issue -> the cost is
// the 8-wave exchange fabric (block barrier across 4 SIMDs, 2-wave/SIMD
// lockstep serialization, 15 DS ops/wave, readlane->SGPR hazards). New
// structure: ONE batch per 128-thread block (2 waves, 1 wave/SIMD). Thread j
// owns elem j and its full-K rows (r,u,n): 3x64 h2 = 96 weight VGPRs.
// Per step: publish z_d[j] as f16 (1 ds_write_b16), 2-wave barrier, read all
// 128 z via 16 broadcast uint4 reads (conflict-free), 192 fdot2 into 12
// accs -> gates are LANE-LOCAL: no partial exchange, no readlane, no shfl.
// LDS read latency streams under the dot issue (compiler-counted lgkmcnt).
// Z double-buffered -> 1 barrier/step; vmcnt never drained (bar_lds).
// Inactive tail steps (t >= len, block-uniform) skip everything heavy.
#define DOT4(QW, M0)                                                          \
  { h2 zk0 = __builtin_bit_cast(h2, (QW).x);                                  \
    ar0 = fdot2f(wr_[(M0) + 0], zk0, ar0);                                    \
    au0 = fdot2f(wu_[(M0) + 0], zk0, au0);                                    \
    an0 = fdot2f(wn_[(M0) + 0], zk0, an0);                                    \
    h2 zk1 = __builtin_bit_cast(h2, (QW).y);                                  \
    ar1 = fdot2f(wr_[(M0) + 1], zk1, ar1);                                    \
    au1 = fdot2f(wu_[(M0) + 1], zk1, au1);                                    \
    an1 = fdot2f(wn_[(M0) + 1], zk1, an1);                                    \
    h2 zk2 = __builtin_bit_cast(h2, (QW).z);                                  \
    ar2 = fdot2f(wr_[(M0) + 2], zk2, ar2);                                    \
    au2 = fdot2f(wu_[(M0) + 2], zk2, au2);                                    \
    an2 = fdot2f(wn_[(M0) + 2], zk2, an2);                                    \
    h2 zk3 = __builtin_bit_cast(h2, (QW).w);                                  \
    ar3 = fdot2f(wr_[(M0) + 3], zk3, ar3);                                    \
    au3 = fdot2f(wu_[(M0) + 3], zk3, au3);                                    \
    an3 = fdot2f(wn_[(M0) + 3], zk3, an3); }

template <typename GT>
__global__ __launch_bounds__(128, 1) void scan_p(
    const float* __restrict__ zinit, const float* __restrict__ tdyn,
    const int* __restrict__ lens, const float* __restrict__ Whh,
    const float* __restrict__ bhh, const float* __restrict__ lgam,
    const GT* __restrict__ gi, float* __restrict__ out)
{
  const int b = blockIdx.x;
  const int j = threadIdx.x;     // elem 0..127 (wave h = j>>6)

  __shared__ __align__(16) u16 Z0[NDZ];   // f16 z_d, double-buffered
  __shared__ __align__(16) u16 Z1[NDZ];

  // full-K weight rows j, j+128, j+256 as h2 pairs (96 VGPRs)
  h2 wr_[64], wu_[64], wn_[64];
  {
    const float4* pr = (const float4*)(Whh + (size_t)j * NDZ);
    const float4* pu = (const float4*)(Whh + (size_t)(j + NDZ) * NDZ);
    const float4* pn = (const float4*)(Whh + (size_t)(j + 2 * NDZ) * NDZ);
#pragma unroll
    for (int q = 0; q < 32; ++q) {
      float4 vr = pr[q], vu = pu[q], vn = pn[q];
      wr_[2 * q]     = __builtin_amdgcn_cvt_pkrtz(vr.x, vr.y);
      wr_[2 * q + 1] = __builtin_amdgcn_cvt_pkrtz(vr.z, vr.w);
      wu_[2 * q]     = __builtin_amdgcn_cvt_pkrtz(vu.x, vu.y);
      wu_[2 * q + 1] = __builtin_amdgcn_cvt_pkrtz(vu.z, vu.w);
      wn_[2 * q]     = __builtin_amdgcn_cvt_pkrtz(vn.x, vn.y);
      wn_[2 * q + 1] = __builtin_amdgcn_cvt_pkrtz(vn.z, vn.w);
    }
  }

  const int len = lens[b];
  const float* tp = tdyn + (size_t)b * NT;
  const GT* gb = gi + (size_t)b * NT * NG;
  float* traj = out + (size_t)NB * NDZ + (size_t)b * NT * NDZ;

  float zc = zinit[b * NDZ + j];
  const float lg = lgam[j];
  const float gam = (lg > 15.f) ? lg : __logf(1.f + __expf(lg));
  const float br = bhh[j], bu = bhh[NDZ + j], bn = bhh[2 * NDZ + j];
  float t_prev = tp[0];
  float zdr = zc;                // z_d(0) = z0 (dt0 = 0)

  // prefetch buffers (static names, 2-step lead)
  float ptkA = tp[1];
  float ptkB = tp[2];
  float pgrA = giload(gb + j), pguA = giload(gb + NDZ + j), pgnA = giload(gb + 2 * NDZ + j);
  float pgrB = giload(gb + NG + j), pguB = giload(gb + NG + NDZ + j), pgnB = giload(gb + NG + 2 * NDZ + j);

  auto stepf = [&](u16* ZB, float& ptkX, float& pgrX, float& pguX, float& pgnX, int t) {
    // off-chain per-step scalars from prefetched data
    const float tk = ptkX;
    const float ef = __expf(-gam * fmaxf(tk - t_prev, 0.f));
    t_prev = tk;
    const float crX = br + pgrX;    // bias+gi folded off the dot chain
    const float cuX = bu + pguX;

    const float zd = zdr;
    const bool active = (t < len);  // block-uniform
    if (active) {
      ZB[j] = f2h16(zd);            // publish own z_d (1 ds_write_b16)
    }
    bar_lds();  // ONLY barrier of the step (2-wave; Z double-buffered)

    if (active) {
      float ar0 = 0.f, ar1 = 0.f, ar2 = 0.f, ar3 = 0.f;
      float au0 = 0.f, au1 = 0.f, au2 = 0.f, au3 = 0.f;
      float an0 = 0.f, an1 = 0.f, an2 = 0.f, an3 = 0.f;
      const uint4* zr = (const uint4*)ZB;   // 128 f16 = 16 broadcast uint4
#pragma unroll
      for (int rr = 0; rr < 16; ++rr) {
        uint4 qv = zr[rr];
        DOT4(qv, rr * 4);
      }
      const float sr = (ar0 + ar1) + (ar2 + ar3);
      const float su = (au0 + au1) + (au2 + au3);
      const float sn = (an0 + an1) + (an2 + an3);
      const float r = sigmoid_f(sr + crX);
      const float u = sigmoid_f(su + cuX);
      const float n = tanh_f(__builtin_fmaf(r, sn + bn, pgnX));
      zc = __builtin_fmaf(u, zd - n, n);   // (1-u)n + u*zd
    } else {
      zc = zd;
    }
    traj[(size_t)t * NDZ + j] = zc;

    zdr = zc * ef;  // z_d(t+1): single mul on the chain

    // prefetch for step t+2 (clamped; values unused past the end)
    const int t2 = (t + 2 < NT) ? (t + 2) : (NT - 1);
    const int t3 = (t + 3 < NT) ? (t + 3) : (NT - 1);
    ptkX = tp[t3];
    const GT* g2 = gb + (size_t)t2 * NG;
    pgrX = giload(g2 + j);
    pguX = giload(g2 + NDZ + j);
    pgnX = giload(g2 + 2 * NDZ + j);
  };

  for (int t = 0; t < NT; t += 2) {
    stepf(Z0, ptkA, pgrA, pguA, pgnA, t);
    stepf(Z1, ptkB, pgrB, pguB, pgnB, t + 1);
  }
  out[b * NDZ + j] = zc;  // z_final
}

extern "C" void kernel_launch(void* const* d_in, const int* in_sizes, int n_in,
                              void* d_out, int out_size, void* d_ws, size_t ws_size,
                              hipStream_t stream) {
  const float* z0   = (const float*)d_in[0];
  const float* tdyn = (const float*)d_in[1];
  const float* Y    = (const float*)d_in[2];
  const float* M    = (const float*)d_in[3];
  const int*   lens = (const int*)d_in[4];
  const float* H    = (const float*)d_in[5];
  const float* Wih  = (const float*)d_in[6];
  const float* bih  = (const float*)d_in[7];
  const float* Whh  = (const float*)d_in[8];
  const float* bhh  = (const float*)d_in[9];
  const float* lgam = (const float*)d_in[10];
  float* out = (float*)d_out;  // f32: [B*DZ] z_final, then [B*T*DZ] Z_traj

  const size_t needF32 = (size_t)NB * NT * NG * sizeof(float);  // 201.3 MB
  dim3 ggrid((NB * NT) / GM, NG / GN);
  if (ws_size >= needF32) {
    float* gi = (float*)d_ws;
    gemm_gi<float><<<ggrid, 256, 0, stream>>>(Y, M, H, Wih, bih, gi);
    scan_p<float><<<dim3(NB), 128, 0, stream>>>(z0, tdyn, lens, Whh, bhh, lgam, gi, out);
  } else {
    u16* gi = (u16*)d_ws;  // bf16 gi (validated: absmax 3.9e-3)
    gemm_gi<u16><<<ggrid, 256, 0, stream>>>(Y, M, H, Wih, bih, gi);
    scan_p<u16><<<dim3(NB), 128, 0, stream>>>(z0, tdyn, lens, Whh, bhh, lgam, gi, out);
  }
}